// Round 1
// baseline (3006.390 us; speedup 1.0000x reference)
//
#include <hip/hip_runtime.h>

typedef _Float16 half8 __attribute__((ext_vector_type(8)));
typedef float f32x4 __attribute__((ext_vector_type(4)));

#define NT 512   // timesteps
#define NB 128   // batch
#define NI 256   // input dim
#define NH 512   // hidden dim

// ---------------------------------------------------------------------------
// Transform W (fp32 row-major [N][K]) -> fragment-linear f16 for MFMA B-operand.
// Block b = t_n*KT + t_k; within block, lane l (0..63) holds 8 elems:
//   n = t_n*16 + (l&15),  k = t_k*32 + (l>>4)*8 + j   (j = 0..7)
// so a wave's 64 lanes read one contiguous 1 KB chunk per MFMA.
// ---------------------------------------------------------------------------
__global__ void w_transform(const float* __restrict__ Whh,
                            const float* __restrict__ Win,
                            _Float16* __restrict__ Wf_hh,
                            _Float16* __restrict__ Wf_in) {
  int tid = blockIdx.x * blockDim.x + threadIdx.x;
  if (tid < 512 * 64) {                 // W_hh: 32 n-tiles * 16 k-tiles
    int l = tid & 63, b = tid >> 6;
    int tk = b & 15, tn = b >> 4;       // b = tn*16 + tk
    int n = tn * 16 + (l & 15);
    int k = tk * 32 + (l >> 4) * 8;
    const float* src = Whh + (size_t)n * NH + k;
    _Float16* dst = Wf_hh + (size_t)tid * 8;
#pragma unroll
    for (int j = 0; j < 8; ++j) dst[j] = (_Float16)src[j];
  } else {                              // W_in: 32 n-tiles * 8 k-tiles
    int t2 = tid - 512 * 64;
    int l = t2 & 63, b = t2 >> 6;
    int tk = b & 7, tn = b >> 3;        // b = tn*8 + tk
    int n = tn * 16 + (l & 15);
    int k = tk * 32 + (l >> 4) * 8;
    const float* src = Win + (size_t)n * NI + k;
    _Float16* dst = Wf_in + (size_t)t2 * 8;
#pragma unroll
    for (int j = 0; j < 8; ++j) dst[j] = (_Float16)src[j];
  }
}

// ---------------------------------------------------------------------------
// Phase 1: xin[m][n] = sum_k x[m][k] * W_in[n][k], M=65536, K=256, N=512.
// One wg (4 waves) per 16-row M-tile; wave w covers n in [w*128, w*128+128).
// Output fp32 straight into d_out (phase 2 consumes + overwrites in place).
// ---------------------------------------------------------------------------
__global__ __launch_bounds__(256)
void input_proj(const float* __restrict__ x,
                const _Float16* __restrict__ Wf_in,
                float* __restrict__ xin) {
  int lane = threadIdx.x & 63;
  int wv = threadIdx.x >> 6;            // 0..3
  int m0 = blockIdx.x * 16;
  int c = lane & 15, q = lane >> 4;
  int row = m0 + c;

  f32x4 acc[8];
#pragma unroll
  for (int i = 0; i < 8; ++i) acc[i] = (f32x4){0.f, 0.f, 0.f, 0.f};

#pragma unroll
  for (int kc = 0; kc < 8; ++kc) {      // k = kc*32
    // A-fragment: x[row][kc*32 + q*8 .. +8], fp32 -> f16
    const float4* ap = (const float4*)(x + (size_t)row * NI + kc * 32 + q * 8);
    float4 a0 = ap[0], a1 = ap[1];
    half8 a;
    a[0] = (_Float16)a0.x; a[1] = (_Float16)a0.y;
    a[2] = (_Float16)a0.z; a[3] = (_Float16)a0.w;
    a[4] = (_Float16)a1.x; a[5] = (_Float16)a1.y;
    a[6] = (_Float16)a1.z; a[7] = (_Float16)a1.w;
#pragma unroll
    for (int nt = 0; nt < 8; ++nt) {
      int tn = wv * 8 + nt;
      const half8* bp =
          (const half8*)(Wf_in + (((size_t)(tn * 8 + kc)) * 64 + lane) * 8);
      acc[nt] = __builtin_amdgcn_mfma_f32_16x16x32_f16(a, *bp, acc[nt], 0, 0, 0);
    }
  }
  // C/D layout: lane l, reg r -> row m = (l>>4)*4 + r, col = base + (l&15)
#pragma unroll
  for (int nt = 0; nt < 8; ++nt) {
    int n = wv * 128 + nt * 16 + c;
#pragma unroll
    for (int r = 0; r < 4; ++r) {
      int m = q * 4 + r;
      xin[(size_t)(m0 + m) * NH + n] = acc[nt][r];
    }
  }
}

// ---------------------------------------------------------------------------
// Phase 2: persistent recurrence. 8 wgs x 1024 threads (16 waves).
// wg g owns batch rows [g*16, g*16+16) for the entire T loop — no cross-wg
// dependence. h kept in LDS: fp32 master (precision) + f16 copy (MFMA A).
// Per step: stage xin_t (32 KB), 32 MFMAs/wave vs streamed Wf_hh (L2-hot),
// fused relu/leak epilogue writes h back + output row. 2 barriers/step.
// ---------------------------------------------------------------------------
__global__ __launch_bounds__(1024)
void recurrence(float* __restrict__ dout,          // [T*B][H] xin -> h, + final
                const float* __restrict__ h0,      // [B][H]
                const _Float16* __restrict__ Wf_hh) {
  __shared__ float    h_f32[16][516];   // stride 516: 2-way bank alias (free)
  __shared__ float    xin_s[16][516];
  __shared__ _Float16 h_f16[16][520];   // stride 520: 16B-aligned rows, 2-way

  int m0 = blockIdx.x * 16;
  int tid = threadIdx.x;
  int lane = tid & 63, wv = tid >> 6;   // wv 0..15
  int c = lane & 15, q = lane >> 4;

  // init h from hidden input
  for (int i = tid; i < 16 * 512; i += 1024) {
    int m = i >> 9, n = i & 511;
    float v = h0[(size_t)(m0 + m) * NH + n];
    h_f32[m][n] = v;
    h_f16[m][n] = (_Float16)v;
  }
  __syncthreads();

  int tn0 = wv * 2;                     // this wave's two 16-col n-tiles

#pragma unroll 1
  for (int t = 0; t < NT; ++t) {
    // ---- stage xin_t (reads region that this step's epilogue overwrites;
    //      same wg + barriers => ordered)
    {
      const float* xp = dout + ((size_t)t * NB + m0) * NH;
#pragma unroll
      for (int i2 = 0; i2 < 2; ++i2) {
        int i = tid + i2 * 1024;        // 0..2047 float4 slots
        int m = i >> 7, n4 = (i & 127) * 4;
        float4 v = *(const float4*)(xp + (size_t)m * NH + n4);
        *(float4*)&xin_s[m][n4] = v;
      }
    }

    // ---- P = h @ W_hh^T for this wave's 32 output cols, K=512
    f32x4 acc0 = (f32x4){0.f, 0.f, 0.f, 0.f};
    f32x4 acc1 = (f32x4){0.f, 0.f, 0.f, 0.f};
#pragma unroll
    for (int kc = 0; kc < 16; ++kc) {
      half8 a = *(const half8*)&h_f16[c][kc * 32 + q * 8];
      half8 b0 = *(const half8*)(Wf_hh +
                   (((size_t)(tn0 * 16 + kc)) * 64 + lane) * 8);
      half8 b1 = *(const half8*)(Wf_hh +
                   (((size_t)((tn0 + 1) * 16 + kc)) * 64 + lane) * 8);
      acc0 = __builtin_amdgcn_mfma_f32_16x16x32_f16(a, b0, acc0, 0, 0, 0);
      acc1 = __builtin_amdgcn_mfma_f32_16x16x32_f16(a, b1, acc1, 0, 0, 0);
    }
    __syncthreads();   // all A-reads of h_f16 done; xin staged by all threads

    // ---- epilogue: h_new = relu(0.8 h + 0.2 (xin + P))
#pragma unroll
    for (int hh = 0; hh < 2; ++hh) {
      f32x4 acc = hh ? acc1 : acc0;
      int n = (tn0 + hh) * 16 + c;
#pragma unroll
      for (int r = 0; r < 4; ++r) {
        int m = q * 4 + r;
        float hv = h_f32[m][n];
        float xv = xin_s[m][n];
        float hn = 0.8f * hv + 0.2f * (xv + acc[r]);
        hn = fmaxf(hn, 0.f);
        h_f32[m][n] = hn;
        h_f16[m][n] = (_Float16)hn;
        dout[((size_t)t * NB + (m0 + m)) * NH + n] = hn;
        if (t == NT - 1) {
          dout[(size_t)NT * NB * NH + (size_t)(m0 + m) * NH + n] = hn;
        }
      }
    }
    __syncthreads();   // h writes visible before next step's A-reads
  }
}

// ---------------------------------------------------------------------------
extern "C" void kernel_launch(void* const* d_in, const int* in_sizes, int n_in,
                              void* d_out, int out_size, void* d_ws,
                              size_t ws_size, hipStream_t stream) {
  const float* x      = (const float*)d_in[0];   // [512][128][256]
  const float* hidden = (const float*)d_in[1];   // [128][512]
  const float* W_in   = (const float*)d_in[2];   // [512][256]
  const float* W_hh   = (const float*)d_in[3];   // [512][512]
  float* out = (float*)d_out;                    // [512*128*512 + 128*512]

  _Float16* Wf_hh = (_Float16*)d_ws;             // 512 KB
  _Float16* Wf_in = Wf_hh + (size_t)NH * NH;     // 256 KB

  // 32768 (W_hh) + 16384 (W_in) lanes-of-8
  w_transform<<<(32768 + 16384) / 256, 256, 0, stream>>>(W_hh, W_in, Wf_hh, Wf_in);
  input_proj<<<(NT * NB) / 16, 256, 0, stream>>>(x, Wf_in, out);
  recurrence<<<NB / 16, 1024, 0, stream>>>(out, hidden, Wf_hh);
}